// Round 4
// baseline (536.815 us; speedup 1.0000x reference)
//
#include <hip/hip_runtime.h>
#include <math.h>

#define NN 2048
#define CXX 768
#define CSS 384
#define HH 16
#define DHH 48

typedef short bf16x8 __attribute__((ext_vector_type(8)));
typedef float f32x4 __attribute__((ext_vector_type(4)));

#define MFMA16(a,b,c) __builtin_amdgcn_mfma_f32_16x16x32_bf16(a,b,c,0,0,0)

__device__ __forceinline__ unsigned short f2bf(float f){
  unsigned u = __float_as_uint(f);
  u += 0x7FFFu + ((u >> 16) & 1u);
  return (unsigned short)(u >> 16);
}
__device__ __forceinline__ float bf2f(unsigned short u){
  return __uint_as_float(((unsigned)u) << 16);
}
__device__ __forceinline__ void async_copy16(const void* g, void* l){
  __builtin_amdgcn_global_load_lds((const __attribute__((address_space(1))) void*)g,
                                   (__attribute__((address_space(3))) void*)l, 16, 0, 0);
}
// barrier WITHOUT the compiler's vmcnt(0) drain: lets async prefetches stay in
// flight across the sync (the AITER-style pipeline m97's structure can't express)
__device__ __forceinline__ void barrier_lgkm(){
  __asm__ volatile("s_waitcnt lgkmcnt(0)\n\ts_barrier" ::: "memory");
}

__device__ inline float waveReduceSum(float v){
  #pragma unroll
  for(int o=32;o>0;o>>=1) v += __shfl_xor(v,o);
  return v;
}

// ---------------- batched weight fp32 -> bf16 transpose (all 8 matrices) ----------
__global__ __launch_bounds__(256) void transpose_all(
    const float* __restrict__ s0, const float* __restrict__ s1, const float* __restrict__ s2,
    const float* __restrict__ s3, const float* __restrict__ s4, const float* __restrict__ s5,
    const float* __restrict__ s6, const float* __restrict__ s7,
    unsigned short* __restrict__ d_scale, unsigned short* __restrict__ d_bias,
    unsigned short* __restrict__ d_azc, unsigned short* __restrict__ d_qkvg,
    unsigned short* __restrict__ d_out){
  int z = blockIdx.z;
  const float* W; unsigned short* Wt; int K;
  switch(z){
    case 0: W=s0; Wt=d_scale; K=384; break;
    case 1: W=s1; Wt=d_bias;  K=384; break;
    case 2: W=s2; Wt=d_azc;   K=384; break;
    case 3: W=s3; Wt=d_qkvg + 0*589824; K=768; break;
    case 4: W=s4; Wt=d_qkvg + 1*589824; K=768; break;
    case 5: W=s5; Wt=d_qkvg + 2*589824; K=768; break;
    case 6: W=s6; Wt=d_qkvg + 3*589824; K=768; break;
    default: W=s7; Wt=d_out; K=768; break;
  }
  int n0 = blockIdx.x*32, k0 = blockIdx.y*32;
  if(k0 >= K) return;
  __shared__ unsigned short t[32][33];
  int c = threadIdx.x & 31, r = threadIdx.x >> 5;
  #pragma unroll
  for(int i=0;i<32;i+=8){
    float v = W[(size_t)(k0 + r + i)*CXX + n0 + c];
    t[c][r+i] = f2bf(v);
  }
  __syncthreads();
  #pragma unroll
  for(int i=0;i<32;i+=8){
    Wt[(size_t)(n0 + r + i)*K + k0 + c] = t[r+i][c];
  }
}

// ---------------- fused LayerNorms: x (fp32 out) + single_cond (bf16 out) ----------
__global__ __launch_bounds__(384) void ln_fused(const float* __restrict__ x,
    const float* __restrict__ scin, const float* __restrict__ w,
    float* __restrict__ xn, unsigned short* __restrict__ scb){
  int row = blockIdx.x;
  int t = threadIdx.x;
  int wid = t>>6, lane = t&63;
  __shared__ float red[6];
  float a0 = x[(size_t)row*CXX + t];
  float a1 = x[(size_t)row*CXX + 384 + t];
  float s = waveReduceSum(a0+a1);
  if(lane==0) red[wid]=s;
  __syncthreads();
  float mu = (red[0]+red[1]+red[2]+red[3]+red[4]+red[5]) * (1.0f/CXX);
  float d0=a0-mu, d1=a1-mu;
  float q = waveReduceSum(d0*d0+d1*d1);
  __syncthreads();
  if(lane==0) red[wid]=q;
  __syncthreads();
  float var = (red[0]+red[1]+red[2]+red[3]+red[4]+red[5]) * (1.0f/CXX);
  float r = rsqrtf(var + 1e-5f);
  xn[(size_t)row*CXX + t] = d0*r;
  xn[(size_t)row*CXX + 384 + t] = d1*r;
  float b = scin[(size_t)row*CSS + t];
  float s2 = waveReduceSum(b);
  __syncthreads();
  if(lane==0) red[wid]=s2;
  __syncthreads();
  float mu2 = (red[0]+red[1]+red[2]+red[3]+red[4]+red[5]) * (1.0f/CSS);
  float d2 = b - mu2;
  float q2 = waveReduceSum(d2*d2);
  __syncthreads();
  if(lane==0) red[wid]=q2;
  __syncthreads();
  float var2 = (red[0]+red[1]+red[2]+red[3]+red[4]+red[5]) * (1.0f/CSS);
  float r2 = rsqrtf(var2 + 1e-5f);
  scb[(size_t)row*CSS + t] = f2bf(d2*r2*w[t]);
}

// ---------------- qkvg GEMM (128x128 tile): C(2048 x 3072) bf16 ----------------
__global__ __launch_bounds__(256) void gemm_qkvg(const unsigned short* __restrict__ A,
    const unsigned short* __restrict__ Bt, const float* __restrict__ bias,
    unsigned short* __restrict__ C){
  __shared__ unsigned short As[128*32];
  __shared__ unsigned short Bs[128*32];
  const int tid = threadIdx.x;
  const int w = tid>>6, lane = tid&63;
  const int ln15 = lane&15, hi = lane>>4;
  const int wm = w&1, wn = w>>1;
  const int m0 = blockIdx.y*128, n0 = blockIdx.x*128;
  const int lrow = lane>>2, lk = (lane&3)*8;
  const int K = 768, NC = 3072;

  f32x4 z = {0.f,0.f,0.f,0.f};
  f32x4 acc[4][4];
  #pragma unroll
  for(int i=0;i<4;i++)
    #pragma unroll
    for(int j=0;j<4;j++) acc[i][j] = z;

  for(int k0=0;k0<K;k0+=32){
    const unsigned short* ga = A + (size_t)(m0 + w*32 + lrow)*K + k0 + lk;
    const unsigned short* gb = Bt + (size_t)(n0 + w*32 + lrow)*K + k0 + lk;
    async_copy16(ga,          &As[w*1024]);
    async_copy16(ga + 16*K,   &As[w*1024 + 512]);
    async_copy16(gb,          &Bs[w*1024]);
    async_copy16(gb + 16*K,   &Bs[w*1024 + 512]);
    __syncthreads();
    bf16x8 af[4], bfr[4];
    #pragma unroll
    for(int i=0;i<4;i++) af[i]  = *(const bf16x8*)&As[(wm*64 + i*16 + ln15)*32 + hi*8];
    #pragma unroll
    for(int j=0;j<4;j++) bfr[j] = *(const bf16x8*)&Bs[(wn*64 + j*16 + ln15)*32 + hi*8];
    #pragma unroll
    for(int i=0;i<4;i++)
      #pragma unroll
      for(int j=0;j<4;j++)
        acc[i][j] = MFMA16(af[i], bfr[j], acc[i][j]);
    __syncthreads();
  }

  #pragma unroll
  for(int i=0;i<4;i++)
    #pragma unroll
    for(int j=0;j<4;j++)
      #pragma unroll
      for(int r=0;r<4;r++){
        int gm = m0 + wm*64 + i*16 + hi*4 + r;
        int gn = n0 + wn*64 + j*16 + ln15;
        float v = acc[i][j][r];
        if(gn < 768) v += bias[gn];
        if(gn >= 2304) v = 1.0f/(1.0f + __expf(-v));
        C[(size_t)gm*NC + gn] = f2bf(v);
      }
}

// ---------------- AdaLN triple-GEMM (64x64 tile, 384 blocks) ----------------
__global__ __launch_bounds__(256) void adaln3(const unsigned short* __restrict__ A,
    const unsigned short* __restrict__ B1, const unsigned short* __restrict__ B2,
    const unsigned short* __restrict__ B3, const float* __restrict__ bs,
    const float* __restrict__ zb, const float* __restrict__ xn,
    unsigned short* __restrict__ xa, float* __restrict__ azc){
  __shared__ unsigned short As[64*32];
  __shared__ unsigned short Bs1[64*32];
  __shared__ unsigned short Bs2[64*32];
  __shared__ unsigned short Bs3[64*32];
  const int tid = threadIdx.x;
  const int w = tid>>6, lane = tid&63;
  const int ln15 = lane&15, hi = lane>>4;
  const int wm = w&1, wn = w>>1;
  const int m0 = blockIdx.y*64, n0 = blockIdx.x*64;
  const int lrow = tid>>2, lk = (tid&3)*8;
  const int K = CSS;

  f32x4 z = {0.f,0.f,0.f,0.f};
  f32x4 acc1[2][2], acc2[2][2], acc3[2][2];
  #pragma unroll
  for(int i=0;i<2;i++)
    #pragma unroll
    for(int j=0;j<2;j++){ acc1[i][j]=z; acc2[i][j]=z; acc3[i][j]=z; }

  for(int k0=0;k0<K;k0+=32){
    async_copy16(A  + (size_t)(m0+lrow)*K + k0 + lk, &As [w*512]);
    async_copy16(B1 + (size_t)(n0+lrow)*K + k0 + lk, &Bs1[w*512]);
    async_copy16(B2 + (size_t)(n0+lrow)*K + k0 + lk, &Bs2[w*512]);
    async_copy16(B3 + (size_t)(n0+lrow)*K + k0 + lk, &Bs3[w*512]);
    __syncthreads();
    bf16x8 af[2], b1f[2], b2f[2], b3f[2];
    #pragma unroll
    for(int i=0;i<2;i++) af[i]  = *(const bf16x8*)&As[(wm*32 + i*16 + ln15)*32 + hi*8];
    #pragma unroll
    for(int j=0;j<2;j++){
      b1f[j] = *(const bf16x8*)&Bs1[(wn*32 + j*16 + ln15)*32 + hi*8];
      b2f[j] = *(const bf16x8*)&Bs2[(wn*32 + j*16 + ln15)*32 + hi*8];
      b3f[j] = *(const bf16x8*)&Bs3[(wn*32 + j*16 + ln15)*32 + hi*8];
    }
    #pragma unroll
    for(int i=0;i<2;i++)
      #pragma unroll
      for(int j=0;j<2;j++){
        acc1[i][j] = MFMA16(af[i], b1f[j], acc1[i][j]);
        acc2[i][j] = MFMA16(af[i], b2f[j], acc2[i][j]);
        acc3[i][j] = MFMA16(af[i], b3f[j], acc3[i][j]);
      }
    __syncthreads();
  }

  #pragma unroll
  for(int i=0;i<2;i++)
    #pragma unroll
    for(int j=0;j<2;j++)
      #pragma unroll
      for(int r=0;r<4;r++){
        int gm = m0 + wm*32 + i*16 + hi*4 + r;
        int gn = n0 + wn*32 + j*16 + ln15;
        float g = 1.0f/(1.0f + __expf(-(acc1[i][j][r] + bs[gn])));
        float v = g * xn[(size_t)gm*CXX + gn] + acc2[i][j][r];
        xa[(size_t)gm*CXX + gn] = f2bf(v);
        azc[(size_t)gm*CXX + gn] = 1.0f/(1.0f + __expf(-(acc3[i][j][r] + zb[gn])));
      }
}

// ---------------- out GEMM (64x64 tile): out = (wag @ out_w) * azc, fp32 ----------
__global__ __launch_bounds__(256) void gemm_out(const unsigned short* __restrict__ A,
    const unsigned short* __restrict__ Bt, const float* __restrict__ mul,
    float* __restrict__ C){
  __shared__ unsigned short As[64*32];
  __shared__ unsigned short Bs[64*32];
  const int tid = threadIdx.x;
  const int w = tid>>6, lane = tid&63;
  const int ln15 = lane&15, hi = lane>>4;
  const int wm = w&1, wn = w>>1;
  const int m0 = blockIdx.y*64, n0 = blockIdx.x*64;
  const int lrow = tid>>2, lk = (tid&3)*8;
  const int K = 768;

  f32x4 z = {0.f,0.f,0.f,0.f};
  f32x4 acc[2][2];
  #pragma unroll
  for(int i=0;i<2;i++)
    #pragma unroll
    for(int j=0;j<2;j++) acc[i][j]=z;

  for(int k0=0;k0<K;k0+=32){
    async_copy16(A  + (size_t)(m0+lrow)*K + k0 + lk, &As[w*512]);
    async_copy16(Bt + (size_t)(n0+lrow)*K + k0 + lk, &Bs[w*512]);
    __syncthreads();
    bf16x8 af[2], bfr[2];
    #pragma unroll
    for(int i=0;i<2;i++) af[i]  = *(const bf16x8*)&As[(wm*32 + i*16 + ln15)*32 + hi*8];
    #pragma unroll
    for(int j=0;j<2;j++) bfr[j] = *(const bf16x8*)&Bs[(wn*32 + j*16 + ln15)*32 + hi*8];
    #pragma unroll
    for(int i=0;i<2;i++)
      #pragma unroll
      for(int j=0;j<2;j++)
        acc[i][j] = MFMA16(af[i], bfr[j], acc[i][j]);
    __syncthreads();
  }

  #pragma unroll
  for(int i=0;i<2;i++)
    #pragma unroll
    for(int j=0;j<2;j++)
      #pragma unroll
      for(int r=0;r<4;r++){
        int gm = m0 + wm*32 + i*16 + hi*4 + r;
        int gn = n0 + wn*32 + j*16 + ln15;
        C[(size_t)gm*CXX + gn] = acc[i][j][r] * mul[(size_t)gm*CXX + gn];
      }
}

// ---------------- MFMA flash attention: async pair dbuf + no-drain barriers -------
__global__ __launch_bounds__(256) void attn_mfma(const unsigned short* __restrict__ qkvg,
    const float* __restrict__ pair, const int* __restrict__ mask,
    unsigned short* __restrict__ wag){
  const int h = blockIdx.y;
  const int q0 = blockIdx.x*64;
  const int tid = threadIdx.x;
  const int w = tid>>6, lane = tid&63;
  const int ln15 = lane&15, hi = lane>>4;

  __shared__ unsigned short Qs[64*72];
  __shared__ unsigned short Ks[64*72];
  __shared__ unsigned short VsT[48*72];
  __shared__ unsigned short Ps[4][16*72];
  __shared__ float PairB[2][64*64];   // double-buffered pair tile (async-filled)

  for(int idx=tid; idx<64*16; idx+=256){
    int row = idx>>4, d = 48 + (idx&15);
    Qs[row*72 + d] = 0;
    Ks[row*72 + d] = 0;
  }
  for(int idx=tid; idx<64*12; idx+=256){
    int qr = idx&63, d0 = (idx>>6)*4;
    ushort4 v = *(const ushort4*)&qkvg[(size_t)(q0+qr)*3072 + h*DHH + d0];
    *(ushort4*)&Qs[qr*72 + d0] = v;
  }

  // ---- prologue prefetch of tile 0: pair (async->LDS buf0), K/V/mask (regs) ----
  const float* pwave = pair + ((size_t)h*NN + (size_t)(q0 + w*16))*NN + ln15*4;
  {
    float* lb = &PairB[0][(w*16)*64];
    #pragma unroll
    for(int it=0;it<4;it++)
      async_copy16(pwave + (size_t)(it*4 + hi)*NN, lb + it*4*64);
  }
  ushort4 kreg[3], vreg[3];
  int mreg[4];
  #pragma unroll
  for(int it=0;it<3;it++){
    int idx = tid + it*256;
    int key = idx&63, d0 = (idx>>6)*4;
    kreg[it] = *(const ushort4*)&qkvg[(size_t)key*3072 +  768 + h*DHH + d0];
    vreg[it] = *(const ushort4*)&qkvg[(size_t)key*3072 + 1536 + h*DHH + d0];
  }
  #pragma unroll
  for(int jt=0;jt<4;jt++) mreg[jt] = mask[jt*16 + ln15];

  __syncthreads();   // Qs staging visible

  bf16x8 aq0 = *(const bf16x8*)&Qs[(w*16+ln15)*72 + hi*8];
  bf16x8 aq1 = *(const bf16x8*)&Qs[(w*16+ln15)*72 + 32 + hi*8];

  f32x4 z = {0.f,0.f,0.f,0.f};
  f32x4 oacc[3] = {z,z,z};
  float mold[4] = {-1e30f,-1e30f,-1e30f,-1e30f};
  float l[4] = {0.f,0.f,0.f,0.f};
  const float scale = 0.14433756729740643f;
  const int qrb = w*16 + hi*4;

  for(int kt=0; kt<NN/64; ++kt){
    barrier_lgkm();   // prev tile's LDS reads done everywhere; NO vmem drain
    // K/V regs -> LDS (compiler inserts the one vmcnt wait here; pair[kt] is
    // older than kreg[kt], so it is complete too)
    #pragma unroll
    for(int it=0;it<3;it++){
      int idx = tid + it*256;
      int key = idx&63, d0 = (idx>>6)*4;
      ushort4 kv = kreg[it];
      *(ushort4*)&Ks[key*72 + d0] = kv;
      ushort4 vv = vreg[it];
      VsT[(d0+0)*72 + key] = vv.x;
      VsT[(d0+1)*72 + key] = vv.y;
      VsT[(d0+2)*72 + key] = vv.z;
      VsT[(d0+3)*72 + key] = vv.w;
    }
    int mc[4];
    #pragma unroll
    for(int jt=0;jt<4;jt++) mc[jt] = mreg[jt];

    // issue next tile's prefetches (stay in flight across barrier_lgkm)
    {
      int k0n = (kt < NN/64 - 1) ? (kt+1)*64 : 0;
      float* lb = &PairB[(kt+1)&1][(w*16)*64];
      #pragma unroll
      for(int it=0;it<4;it++)
        async_copy16(pwave + k0n + (size_t)(it*4 + hi)*NN, lb + it*4*64);
      #pragma unroll
      for(int it=0;it<3;it++){
        int idx = tid + it*256;
        int key = idx&63, d0 = (idx>>6)*4;
        kreg[it] = *(const ushort4*)&qkvg[(size_t)(k0n+key)*3072 +  768 + h*DHH + d0];
        vreg[it] = *(const ushort4*)&qkvg[(size_t)(k0n+key)*3072 + 1536 + h*DHH + d0];
      }
      #pragma unroll
      for(int jt=0;jt<4;jt++) mreg[jt] = mask[k0n + jt*16 + ln15];
    }
    barrier_lgkm();   // Ks/VsT visible; prefetches still in flight

    const float* pcur = &PairB[kt&1][0];

    // S = Q K^T
    f32x4 sreg[4];
    #pragma unroll
    for(int jt=0;jt<4;jt++){
      bf16x8 bk0 = *(const bf16x8*)&Ks[(jt*16+ln15)*72 + hi*8];
      bf16x8 bk1 = *(const bf16x8*)&Ks[(jt*16+ln15)*72 + 32 + hi*8];
      f32x4 s = z;
      s = MFMA16(aq0, bk0, s);
      s = MFMA16(aq1, bk1, s);
      sreg[jt] = s;
    }

    float sv[4][4];
    #pragma unroll
    for(int jt=0;jt<4;jt++)
      #pragma unroll
      for(int r=0;r<4;r++){
        float pv_ = pcur[(qrb + r)*64 + jt*16 + ln15];
        sv[jt][r] = mc[jt] ? sreg[jt][r]*scale + pv_ : -1e9f;
      }

    // online softmax
    float mr[4], al[4], rs[4];
    #pragma unroll
    for(int r=0;r<4;r++)
      mr[r] = fmaxf(fmaxf(sv[0][r],sv[1][r]), fmaxf(sv[2][r],sv[3][r]));
    #pragma unroll
    for(int o=1;o<16;o<<=1)
      #pragma unroll
      for(int r=0;r<4;r++) mr[r] = fmaxf(mr[r], __shfl_xor(mr[r],o));
    #pragma unroll
    for(int r=0;r<4;r++){
      float mn = fmaxf(mold[r], mr[r]);
      al[r] = __expf(mold[r] - mn);
      mold[r] = mn;
    }
    float pv[4][4];
    #pragma unroll
    for(int jt=0;jt<4;jt++)
      #pragma unroll
      for(int r=0;r<4;r++)
        pv[jt][r] = __expf(sv[jt][r] - mold[r]);
    #pragma unroll
    for(int r=0;r<4;r++) rs[r] = pv[0][r]+pv[1][r]+pv[2][r]+pv[3][r];
    #pragma unroll
    for(int o=1;o<16;o<<=1)
      #pragma unroll
      for(int r=0;r<4;r++) rs[r] += __shfl_xor(rs[r],o);
    #pragma unroll
    for(int r=0;r<4;r++) l[r] = l[r]*al[r] + rs[r];

    // P -> per-wave LDS (A-frag layout round trip)
    #pragma unroll
    for(int jt=0;jt<4;jt++)
      #pragma unroll
      for(int r=0;r<4;r++)
        Ps[w][(hi*4+r)*72 + jt*16 + ln15] = f2bf(pv[jt][r]);
    __asm__ volatile("s_waitcnt lgkmcnt(0)" ::: "memory");

    #pragma unroll
    for(int dt=0;dt<3;dt++)
      #pragma unroll
      for(int r=0;r<4;r++) oacc[dt][r] *= al[r];

    bf16x8 ap0 = *(const bf16x8*)&Ps[w][ln15*72 + hi*8];
    bf16x8 ap1 = *(const bf16x8*)&Ps[w][ln15*72 + 32 + hi*8];
    #pragma unroll
    for(int dt=0;dt<3;dt++){
      bf16x8 bv0 = *(const bf16x8*)&VsT[(dt*16+ln15)*72 + hi*8];
      bf16x8 bv1 = *(const bf16x8*)&VsT[(dt*16+ln15)*72 + 32 + hi*8];
      oacc[dt] = MFMA16(ap0, bv0, oacc[dt]);
      oacc[dt] = MFMA16(ap1, bv1, oacc[dt]);
    }
  }

  #pragma unroll
  for(int r=0;r<4;r++){
    float linv = 1.0f / l[r];
    int qrow = q0 + qrb + r;
    #pragma unroll
    for(int dt=0;dt<3;dt++){
      int col = h*DHH + dt*16 + ln15;
      float g = bf2f(qkvg[(size_t)qrow*3072 + 2304 + col]);
      float o = oacc[dt][r] * linv * g;
      wag[(size_t)qrow*CXX + col] = f2bf(o);
    }
  }
}

extern "C" void kernel_launch(void* const* d_in, const int* in_sizes, int n_in,
                              void* d_out, int out_size, void* d_ws, size_t ws_size,
                              hipStream_t stream) {
  const float* x           = (const float*)d_in[0];
  const int*   mask        = (const int*)  d_in[1];
  const float* pair        = (const float*)d_in[2];
  const float* single_cond = (const float*)d_in[3];
  const float* ln_sc_w     = (const float*)d_in[4];
  const float* sc_scale_w  = (const float*)d_in[5];
  const float* sc_scale_b  = (const float*)d_in[6];
  const float* sc_bias_w   = (const float*)d_in[7];
  const float* q_w         = (const float*)d_in[8];
  const float* q_b         = (const float*)d_in[9];
  const float* k_w         = (const float*)d_in[10];
  const float* v_w         = (const float*)d_in[11];
  const float* gate_w      = (const float*)d_in[12];
  const float* out_w       = (const float*)d_in[13];
  const float* azc_w       = (const float*)d_in[14];
  const float* azc_b       = (const float*)d_in[15];
  float* out = (float*)d_out;

  unsigned short* p = (unsigned short*)d_ws;
  unsigned short* Wt_scale = p;  p += 768*384;
  unsigned short* Wt_bias  = p;  p += 768*384;
  unsigned short* Wt_azc   = p;  p += 768*384;
  unsigned short* Wt_out   = p;  p += 768*768;
  unsigned short* Wt_qkvg  = p;  p += (size_t)3072*768;
  unsigned short* scb      = p;  p += 2048*384;
  unsigned short* xa       = p;  p += 2048*768;
  unsigned short* qkvg     = p;  p += (size_t)2048*3072;
  unsigned short* wag      = p;  p += 2048*768;
  float* fp = (float*)p;
  float* xn  = fp; fp += (size_t)2048*768;
  float* azc = fp;

  transpose_all<<<dim3(24,24,8), 256, 0, stream>>>(
      sc_scale_w, sc_bias_w, azc_w, q_w, k_w, v_w, gate_w, out_w,
      Wt_scale, Wt_bias, Wt_azc, Wt_qkvg, Wt_out);

  ln_fused<<<NN, 384, 0, stream>>>(x, single_cond, ln_sc_w, xn, scb);

  adaln3<<<dim3(12,32), 256, 0, stream>>>(scb, Wt_scale, Wt_bias, Wt_azc,
                                          sc_scale_b, azc_b, xn, xa, azc);

  gemm_qkvg<<<dim3(24,16), 256, 0, stream>>>(xa, Wt_qkvg, q_b, qkvg);

  attn_mfma<<<dim3(32,16), 256, 0, stream>>>(qkvg, pair, mask, wag);

  gemm_out<<<dim3(12,32), 256, 0, stream>>>(wag, Wt_out, azc, out);
}